// Round 1
// baseline (354.161 us; speedup 1.0000x reference)
//
#include <hip/hip_runtime.h>

// PairwiseCost: out[b,i,j] = max(||x[b,i]||^2 + ||y[b,j]||^2 - 2<x[b,i],y[b,j]>, 0)
// B=16, N=2048, D=128, fp32 in/out. bf16 MFMA for the cross term, fp32-exact norms.

#define Bb   16
#define Nn   2048
#define Dd   128
#define TILE 128
#define LDSS 136   // LDS row stride in bf16 elems: 272 B = 17*16 -> 16B-aligned rows,
                   // spreads b128 reads/writes uniformly over bank-quads (8-phase minimum)

typedef __bf16 bf16x8 __attribute__((ext_vector_type(8)));
typedef float  f32x4  __attribute__((ext_vector_type(4)));

__device__ __forceinline__ unsigned int f2bf(float f) {
  // round-to-nearest-even fp32 -> bf16 bit pattern (low 16 bits of result)
  unsigned int u = __float_as_uint(f);
  return (u + 0x7FFFu + ((u >> 16) & 1u)) >> 16;
}

__global__ __launch_bounds__(256, 2)
void pairwise_cost_kernel(const float* __restrict__ x,
                          const float* __restrict__ y,
                          float* __restrict__ out) {
  __shared__ __align__(16) unsigned short xs[TILE * LDSS];
  __shared__ __align__(16) unsigned short ys[TILE * LDSS];
  __shared__ float xn_s[TILE];
  __shared__ float yn_s[TILE];

  const int t  = threadIdx.x;
  const int b  = blockIdx.z;
  const int i0 = blockIdx.y * TILE;
  const int j0 = blockIdx.x * TILE;

  const int r    = t >> 1;   // 0..127: tile row this thread stages
  const int half = t & 1;    // which 64-element half of the row

  // ---- stage x tile (fp32 -> bf16 in LDS) + fp32 row norms ----
  {
    const float4* src = (const float4*)(x + ((size_t)b * Nn + (i0 + r)) * Dd + half * 64);
    float ss = 0.f;
    #pragma unroll
    for (int q = 0; q < 8; ++q) {
      float4 v0 = src[2 * q];
      float4 v1 = src[2 * q + 1];
      ss += v0.x * v0.x + v0.y * v0.y + v0.z * v0.z + v0.w * v0.w
          + v1.x * v1.x + v1.y * v1.y + v1.z * v1.z + v1.w * v1.w;
      uint4 pk;
      pk.x = f2bf(v0.x) | (f2bf(v0.y) << 16);
      pk.y = f2bf(v0.z) | (f2bf(v0.w) << 16);
      pk.z = f2bf(v1.x) | (f2bf(v1.y) << 16);
      pk.w = f2bf(v1.z) | (f2bf(v1.w) << 16);
      *(uint4*)&xs[r * LDSS + half * 64 + q * 8] = pk;   // 16B ds_write_b128
    }
    ss += __shfl_xor(ss, 1);
    if (half == 0) xn_s[r] = ss;
  }
  // ---- stage y tile ----
  {
    const float4* src = (const float4*)(y + ((size_t)b * Nn + (j0 + r)) * Dd + half * 64);
    float ss = 0.f;
    #pragma unroll
    for (int q = 0; q < 8; ++q) {
      float4 v0 = src[2 * q];
      float4 v1 = src[2 * q + 1];
      ss += v0.x * v0.x + v0.y * v0.y + v0.z * v0.z + v0.w * v0.w
          + v1.x * v1.x + v1.y * v1.y + v1.z * v1.z + v1.w * v1.w;
      uint4 pk;
      pk.x = f2bf(v0.x) | (f2bf(v0.y) << 16);
      pk.y = f2bf(v0.z) | (f2bf(v0.w) << 16);
      pk.z = f2bf(v1.x) | (f2bf(v1.y) << 16);
      pk.w = f2bf(v1.z) | (f2bf(v1.w) << 16);
      *(uint4*)&ys[r * LDSS + half * 64 + q * 8] = pk;
    }
    ss += __shfl_xor(ss, 1);
    if (half == 0) yn_s[r] = ss;
  }
  __syncthreads();

  // ---- MFMA compute: each wave does a 64x64 sub-tile (4x4 of 16x16x32) ----
  const int w    = t >> 6;
  const int lane = t & 63;
  const int lrow = lane & 15;   // A: m-index / B: n-index
  const int quad = lane >> 4;   // k-group
  const int wr   = (w >> 1) * 64;
  const int wc   = (w & 1) * 64;

  f32x4 acc[4][4];
  #pragma unroll
  for (int i = 0; i < 4; ++i)
    #pragma unroll
    for (int j = 0; j < 4; ++j)
      acc[i][j] = (f32x4){0.f, 0.f, 0.f, 0.f};

  #pragma unroll
  for (int k = 0; k < 4; ++k) {
    const int dk = k * 32 + quad * 8;   // d-offset for this lane's 8 bf16 elems
    bf16x8 af[4], bfr[4];
    #pragma unroll
    for (int ti = 0; ti < 4; ++ti)
      af[ti] = *(const bf16x8*)&xs[(wr + ti * 16 + lrow) * LDSS + dk];  // ds_read_b128
    #pragma unroll
    for (int tj = 0; tj < 4; ++tj)
      bfr[tj] = *(const bf16x8*)&ys[(wc + tj * 16 + lrow) * LDSS + dk];
    #pragma unroll
    for (int ti = 0; ti < 4; ++ti)
      #pragma unroll
      for (int tj = 0; tj < 4; ++tj)
        acc[ti][tj] = __builtin_amdgcn_mfma_f32_16x16x32_bf16(af[ti], bfr[tj], acc[ti][tj], 0, 0, 0);
  }

  // ---- epilogue: cost = max(xn + yn - 2*dot, 0); C/D layout col=lane&15, row=quad*4+reg ----
  float* outb = out + (size_t)b * Nn * Nn;
  #pragma unroll
  for (int ti = 0; ti < 4; ++ti) {
    float xn[4];
    #pragma unroll
    for (int rg = 0; rg < 4; ++rg)
      xn[rg] = xn_s[wr + ti * 16 + quad * 4 + rg];
    #pragma unroll
    for (int tj = 0; tj < 4; ++tj) {
      const float yn = yn_s[wc + tj * 16 + lrow];
      const int   jj = j0 + wc + tj * 16 + lrow;
      #pragma unroll
      for (int rg = 0; rg < 4; ++rg) {
        const int ii  = i0 + wr + ti * 16 + quad * 4 + rg;
        float cval    = xn[rg] + yn - 2.0f * acc[ti][tj][rg];
        outb[(size_t)ii * Nn + jj] = fmaxf(cval, 0.0f);
      }
    }
  }
}

extern "C" void kernel_launch(void* const* d_in, const int* in_sizes, int n_in,
                              void* d_out, int out_size, void* d_ws, size_t ws_size,
                              hipStream_t stream) {
  const float* x = (const float*)d_in[0];
  const float* y = (const float*)d_in[1];
  float* out = (float*)d_out;
  dim3 grid(Nn / TILE, Nn / TILE, Bb);
  pairwise_cost_kernel<<<grid, dim3(256, 1, 1), 0, stream>>>(x, y, out);
}